// Round 1
// baseline (2330.259 us; speedup 1.0000x reference)
//
#include <hip/hip_runtime.h>
#include <cstdint>
#include <cstddef>

// ---------------------------------------------------------------------------
// R_GAMLP_RLU: H=10 hops, N=100000 nodes, F=256, HID=512, C=47.
// Plan:
//   attn_kernel : wave-per-node; xl/xr dots + softmax recursion in fp32,
//                 right = sum att_h * f_h  -> bf16 (N x 256)
//   pack_wt     : fp32 weights -> bf16 transposed [Ncols][K], padded (C 47->64)
//   gemm_bt     : m97-style 128x128 bf16 MFMA GEMM, epilogue variants fuse
//                 bias / prelu / residual / sup computation / final add.
// ---------------------------------------------------------------------------

#define DEVI __device__ __forceinline__

typedef __attribute__((ext_vector_type(4))) float fx4;
typedef __attribute__((ext_vector_type(8))) short sx8;

constexpr int NN = 100000;   // nodes (M dimension of all GEMMs)

DEVI unsigned short f2b(float f) {   // fp32 -> bf16 RNE (no NaNs in this net)
  unsigned u = __float_as_uint(f);
  u = (u + 0x7fffu + ((u >> 16) & 1u)) >> 16;
  return (unsigned short)u;
}
DEVI float b2f(short v) {
  return __uint_as_float(((unsigned)(unsigned short)v) << 16);
}

// async global->LDS, 16B per lane (dest must be base + lane*16, no padding)
#define GLDS16(gp, lp) __builtin_amdgcn_global_load_lds( \
    (__attribute__((address_space(1))) void*)(void*)(gp), \
    (__attribute__((address_space(3))) void*)(lp), 16, 0, 0)

// ---------------------------------------------------------------------------
// Attention stage. One wave per node. f[h] float4/lane (40 VGPR), 20 wave
// reductions, then the softmax recursion using xl/xr only (history@wl is
// linear => never materialize history).
// ---------------------------------------------------------------------------
__global__ __launch_bounds__(256)
void attn_kernel(const float* __restrict__ feat, const float* __restrict__ wa,
                 const float* __restrict__ baP, short* __restrict__ right) {
  const int lane = threadIdx.x & 63;
  const int n = blockIdx.x * 4 + (threadIdx.x >> 6);   // 25000*4 == 100000 exactly
  const float ba = *baP;
  const fx4 wl4 = *(const fx4*)(wa + lane * 4);
  const fx4 wr4 = *(const fx4*)(wa + 256 + lane * 4);
  fx4 f[10];
  float xl[10], xr[10];
#pragma unroll
  for (int h = 0; h < 10; h++) {
    f[h] = *(const fx4*)(feat + ((long)h * NN + n) * 256 + lane * 4);
    float pl = f[h][0] * wl4[0] + f[h][1] * wl4[1] + f[h][2] * wl4[2] + f[h][3] * wl4[3];
    float pr = f[h][0] * wr4[0] + f[h][1] * wr4[1] + f[h][2] * wr4[2] + f[h][3] * wr4[3];
#pragma unroll
    for (int off = 32; off > 0; off >>= 1) {
      pl += __shfl_xor(pl, off);
      pr += __shfl_xor(pr, off);
    }
    xl[h] = pl; xr[h] = pr;
  }
  // scalar recursion (wave-uniform): s_i = lrelu(P/S + xr_i + ba)
  float e[10];
  float s = xl[0] + xr[0] + ba;
  s = s >= 0.f ? s : 0.2f * s;
  e[0] = __expf(s);
  float P = e[0] * xl[0], S = e[0];
#pragma unroll
  for (int i = 1; i < 10; i++) {
    float t = P / S + xr[i] + ba;
    t = t >= 0.f ? t : 0.2f * t;
    e[i] = __expf(t);
    P += e[i] * xl[i];
    S += e[i];
  }
  const float inv = 1.f / S;
  fx4 r = {0.f, 0.f, 0.f, 0.f};
#pragma unroll
  for (int h = 0; h < 10; h++) {
    const float w = e[h] * inv;
    r[0] += w * f[h][0]; r[1] += w * f[h][1];
    r[2] += w * f[h][2]; r[3] += w * f[h][3];
  }
  ushort4 o;
  o.x = f2b(r[0]); o.y = f2b(r[1]); o.z = f2b(r[2]); o.w = f2b(r[3]);
  *(ushort4*)(right + (long)n * 256 + lane * 4) = o;
}

// ---------------------------------------------------------------------------
// Weight pack: dst[n][k] (bf16, padK x padN) = src[k][n] (fp32, Ksrc x Nsrc),
// zero-padded. Tiny matrices; layout so GEMM B^T rows are contiguous in K.
// ---------------------------------------------------------------------------
__global__ void pack_wt(const float* __restrict__ src, short* __restrict__ dst,
                        int Ksrc, int Nsrc, int padK, int padN) {
  int idx = blockIdx.x * 256 + threadIdx.x;
  if (idx >= padK * padN) return;
  int n = idx / padK, k = idx - n * padK;
  float v = (k < Ksrc && n < Nsrc) ? src[(long)k * Nsrc + n] : 0.f;
  dst[idx] = (short)f2b(v);
}

// label_emb (N x 47 fp32) -> (N x 64 bf16, zero-padded)
__global__ void pack_lab(const float* __restrict__ src, short* __restrict__ dst) {
  long idx = (long)blockIdx.x * 256 + threadIdx.x;   // over N*64
  if (idx >= (long)NN * 64) return;
  int n = (int)(idx >> 6), k = (int)(idx & 63);
  dst[idx] = (short)f2b(k < 47 ? src[(long)n * 47 + k] : 0.f);
}

// ---------------------------------------------------------------------------
// GEMM: C(M x Nc) = A(M x K, bf16 row-major) * BT(Nc x K, bf16 row-major)^T
// m97 structure: 256 thr / 4 waves, BM=128, BK=32, global_load_lds staging,
// 16x16x32 bf16 MFMA, fp32 acc. Epilogue variants:
//  0: x0 = c + b0           -> out0=x0, out1=sup1=0.5*prelu(x0)+0.5*x0
//  1: x1 = c + prelu(x0)    -> out0=x1, out1=sup2=0.5*prelu(x1)+0.5*x0
//  2: x2 = c + prelu(x1)    -> out0=p2=prelu(x2)
//  3: fout[m*64+n] = c + b_last[n]            (fp32 scratch, Nc=64)
//  4: out0 = prelu(c + bias)                  (label-path layers)
//  5: fout[m*47+n] = c + bl3[n] + xout[m*64+n]  (final, n<47)
// ---------------------------------------------------------------------------
template<int BN, int EPI>
__global__ __launch_bounds__(256)
void gemm_bt(const short* __restrict__ A, const short* __restrict__ BT, const int K,
             const float* __restrict__ bias, const short* __restrict__ epiIn,
             short* __restrict__ out0, short* __restrict__ out1,
             const float* __restrict__ alphaP, const float* __restrict__ xout,
             float* __restrict__ fout) {
  constexpr int BM = 128, BK = 32;
  constexpr int WN = BN / 2;       // 64 (BN=128) or 32 (BN=64)
  constexpr int FM = 4, FN = WN / 16;
  __shared__ short As[BM * BK];
  __shared__ short Bs[BN * BK];
  const int tid = threadIdx.x;
  const int wave = tid >> 6, lane = tid & 63;
  const int wm = wave >> 1, wn = wave & 1;
  const int m0 = blockIdx.x * BM;
  const int n0 = blockIdx.y * BN;
  fx4 acc[FM][FN] = {};

  const int kIters = K / BK;
  for (int kk = 0; kk < kIters; kk++) {
    const int k0 = kk * BK;
#pragma unroll
    for (int c = 0; c < (BM * BK) / (256 * 8); c++) {   // 2 chunks of 16B
      const int idx = c * 256 + tid;
      long row = m0 + (idx >> 2);
      if (row > NN - 1) row = NN - 1;                   // clamp M tail (M=100000)
      const short* gp = A + row * (long)K + k0 + ((idx & 3) << 3);
      GLDS16(gp, As + idx * 8);
    }
#pragma unroll
    for (int c = 0; c < (BN * BK) / (256 * 8); c++) {   // 2 (BN=128) or 1 (BN=64)
      const int idx = c * 256 + tid;
      const short* gp = BT + (long)(n0 + (idx >> 2)) * K + k0 + ((idx & 3) << 3);
      GLDS16(gp, Bs + idx * 8);
    }
    __syncthreads();                                    // drains vmcnt before barrier
    sx8 af[FM], bf[FN];
#pragma unroll
    for (int i = 0; i < FM; i++)
      af[i] = *(const sx8*)(As + (wm * 64 + i * 16 + (lane & 15)) * BK + ((lane >> 4) << 3));
#pragma unroll
    for (int j = 0; j < FN; j++)
      bf[j] = *(const sx8*)(Bs + (wn * WN + j * 16 + (lane & 15)) * BK + ((lane >> 4) << 3));
#pragma unroll
    for (int i = 0; i < FM; i++)
#pragma unroll
      for (int j = 0; j < FN; j++)
        acc[i][j] = __builtin_amdgcn_mfma_f32_16x16x32_bf16(af[i], bf[j], acc[i][j], 0, 0, 0);
    __syncthreads();
  }

  const float alpha = (alphaP != nullptr) ? *alphaP : 0.f;
#pragma unroll
  for (int i = 0; i < FM; i++) {
#pragma unroll
    for (int j = 0; j < FN; j++) {
#pragma unroll
      for (int r = 0; r < 4; r++) {
        const int m = m0 + wm * 64 + i * 16 + ((lane >> 4) << 2) + r;  // C/D: row=(l>>4)*4+reg
        const int n = n0 + wn * WN + j * 16 + (lane & 15);             //      col=l&15
        if (m >= NN) continue;
        float v = acc[i][j][r];
        const long o = (long)m * 512 + n;
        if constexpr (EPI == 0) {
          v += bias[n];
          out0[o] = (short)f2b(v);
          const float p = v >= 0.f ? v : alpha * v;
          out1[o] = (short)f2b(0.5f * p + 0.5f * v);
        } else if constexpr (EPI == 1) {
          const float x0v = b2f(epiIn[o]);
          const float xi = x0v >= 0.f ? x0v : alpha * x0v;
          const float x1 = v + xi;
          out0[o] = (short)f2b(x1);
          const float p1 = x1 >= 0.f ? x1 : alpha * x1;
          out1[o] = (short)f2b(0.5f * p1 + 0.5f * x0v);
        } else if constexpr (EPI == 2) {
          const float x1v = b2f(epiIn[o]);
          const float xi = x1v >= 0.f ? x1v : alpha * x1v;
          const float x2 = v + xi;
          out0[o] = (short)f2b(x2 >= 0.f ? x2 : alpha * x2);
        } else if constexpr (EPI == 3) {
          const float bv = (n < 47) ? bias[n] : 0.f;
          fout[(long)m * 64 + n] = v + bv;
        } else if constexpr (EPI == 4) {
          const float y = v + bias[n];
          out0[o] = (short)f2b(y >= 0.f ? y : alpha * y);
        } else {  // EPI == 5
          if (n < 47) fout[(long)m * 47 + n] = v + bias[n] + xout[(long)m * 64 + n];
        }
      }
    }
  }
}

// ---------------------------------------------------------------------------
// Workspace layout (bytes). Total needed ~502 MB.
// ---------------------------------------------------------------------------
constexpr long  OFF_W0T  = 0;         // shorts: 512x256
constexpr long  OFF_WG1T = 131072;    // 512x512
constexpr long  OFF_WG2T = 393216;    // 512x512
constexpr long  OFF_WLST = 655360;    // 64x512
constexpr long  OFF_WL0T = 688128;    // 512x64
constexpr long  OFF_WL1T = 720896;    // 512x512
constexpr long  OFF_WL2T = 983040;    // 512x512
constexpr long  OFF_WL3T = 1245184;   // 64x512  (ends 1277952 shorts = 2555904 B)
constexpr size_t B_RIGHT = 2560000;      // N*256 bf16 = 51.2 MB
constexpr size_t B_LAB   = 53760000;     // N*64  bf16 = 12.8 MB
constexpr size_t B_XOUT  = 66560000;     // N*64  fp32 = 25.6 MB
constexpr size_t B_B1    = 92160000;     // N*512 bf16 buffers (102.4 MB each)
constexpr size_t B_B2    = 194560000;
constexpr size_t B_B3    = 296960000;
constexpr size_t B_B4    = 399360000;
constexpr size_t WS_NEED = 501760000;

extern "C" void kernel_launch(void* const* d_in, const int* in_sizes, int n_in,
                              void* d_out, int out_size, void* d_ws, size_t ws_size,
                              hipStream_t stream) {
  const float* features  = (const float*)d_in[0];
  const float* label_emb = (const float*)d_in[1];
  const float* wa     = (const float*)d_in[2];
  const float* ba     = (const float*)d_in[3];
  const float* w0     = (const float*)d_in[4];
  const float* b0     = (const float*)d_in[5];
  const float* wg1    = (const float*)d_in[6];
  const float* wg2    = (const float*)d_in[7];
  const float* w_last = (const float*)d_in[8];
  const float* b_last = (const float*)d_in[9];
  const float* a_out  = (const float*)d_in[10];
  const float* wl0    = (const float*)d_in[11];
  const float* bl0    = (const float*)d_in[12];
  const float* wl1    = (const float*)d_in[13];
  const float* bl1    = (const float*)d_in[14];
  const float* wl2    = (const float*)d_in[15];
  const float* bl2    = (const float*)d_in[16];
  const float* wl3    = (const float*)d_in[17];
  const float* bl3    = (const float*)d_in[18];
  const float* a_lab  = (const float*)d_in[19];

  if (ws_size < WS_NEED) return;  // fail loudly (absmax) rather than corrupt memory

  char*  ws    = (char*)d_ws;
  short* WP    = (short*)ws;
  short* right = (short*)(ws + B_RIGHT);
  short* lab   = (short*)(ws + B_LAB);
  float* xoutb = (float*)(ws + B_XOUT);
  short* B1    = (short*)(ws + B_B1);   // x0, later p2
  short* B2    = (short*)(ws + B_B2);   // sup1, later y0
  short* B3    = (short*)(ws + B_B3);   // x1, later y1 / y2... (see schedule)
  short* B4    = (short*)(ws + B_B4);   // sup2, later y1->y2 chain

  auto pk = [&](const float* s, long off, int Ks, int Ns, int pK, int pN) {
    int tot = pK * pN;
    pack_wt<<<dim3((tot + 255) / 256), dim3(256), 0, stream>>>(s, WP + off, Ks, Ns, pK, pN);
  };
  pk(w0,     OFF_W0T,  256, 512, 256, 512);
  pk(wg1,    OFF_WG1T, 512, 512, 512, 512);
  pk(wg2,    OFF_WG2T, 512, 512, 512, 512);
  pk(w_last, OFF_WLST, 512, 47,  512, 64);
  pk(wl0,    OFF_WL0T, 47,  512, 64,  512);
  pk(wl1,    OFF_WL1T, 512, 512, 512, 512);
  pk(wl2,    OFF_WL2T, 512, 512, 512, 512);
  pk(wl3,    OFF_WL3T, 512, 47,  512, 64);
  pack_lab<<<dim3(25000), dim3(256), 0, stream>>>(label_emb, lab);

  attn_kernel<<<dim3(25000), dim3(256), 0, stream>>>(features, wa, ba, right);

  const dim3 blk(256);
  const dim3 g512(782, 4), g64(782, 1);
  // main path
  gemm_bt<128, 0><<<g512, blk, 0, stream>>>(right, WP + OFF_W0T, 256, b0, nullptr,
                                            B1, B2, a_out, nullptr, nullptr);
  gemm_bt<128, 1><<<g512, blk, 0, stream>>>(B2, WP + OFF_WG1T, 512, nullptr, B1,
                                            B3, B4, a_out, nullptr, nullptr);
  gemm_bt<128, 2><<<g512, blk, 0, stream>>>(B4, WP + OFF_WG2T, 512, nullptr, B3,
                                            B1, nullptr, a_out, nullptr, nullptr);
  gemm_bt<64, 3><<<g64, blk, 0, stream>>>(B1, WP + OFF_WLST, 512, b_last, nullptr,
                                          nullptr, nullptr, nullptr, nullptr, xoutb);
  // label path (reuses freed buffers)
  gemm_bt<128, 4><<<g512, blk, 0, stream>>>(lab, WP + OFF_WL0T, 64, bl0, nullptr,
                                            B2, nullptr, a_lab, nullptr, nullptr);
  gemm_bt<128, 4><<<g512, blk, 0, stream>>>(B2, WP + OFF_WL1T, 512, bl1, nullptr,
                                            B3, nullptr, a_lab, nullptr, nullptr);
  gemm_bt<128, 4><<<g512, blk, 0, stream>>>(B3, WP + OFF_WL2T, 512, bl2, nullptr,
                                            B4, nullptr, a_lab, nullptr, nullptr);
  gemm_bt<64, 5><<<g64, blk, 0, stream>>>(B4, WP + OFF_WL3T, 512, bl3, nullptr,
                                          nullptr, nullptr, nullptr, xoutb, (float*)d_out);
}